// Round 2
// baseline (14058.041 us; speedup 1.0000x reference)
//
#include <hip/hip_runtime.h>
#include <hip/hip_bf16.h>
#include <type_traits>

#define NN 50000   // nodes
#define NE 400000  // edges
#define DD 384     // input dim
#define NH 4       // heads
#define HC 512     // heads * per-head dim
// per-head dim C = 128, 1/sqrt(C) = 0.08838834764831845

typedef unsigned int u32;
typedef unsigned short u16;

__device__ __forceinline__ float bflo(u32 u){ return __uint_as_float(u << 16); }
__device__ __forceinline__ float bfhi(u32 u){ return __uint_as_float(u & 0xFFFF0000u); }
__device__ __forceinline__ u16 f2bf(float f){
    u32 u = __float_as_uint(f);
    u32 r = (u + 0x7FFFu + ((u >> 16) & 1u)) >> 16;   // round-to-nearest-even
    return (u16)r;
}
// order-preserving float->uint map for atomicMax-based segment max
__device__ __forceinline__ u32 ordU(float f){
    u32 u = __float_as_uint(f);
    return (u >> 31) ? ~u : (u | 0x80000000u);
}
__device__ __forceinline__ float unordU(u32 t){
    u32 u = (t >> 31) ? (t & 0x7FFFFFFFu) : ~t;
    return __uint_as_float(u);
}

// ---------------------------------------------------------------------------
// Y[n,o] = sum_k X[n,k] * W[o,k] + b[o]
// X: n x K row-major (IT = float or u16/bf16), W: O x K row-major fp32.
// BM=BN=64, BK=16, 256 threads, 4x4 micro-tile. OT = u16 (bf16) or float.
// ---------------------------------------------------------------------------
template<typename IT, typename OT>
__global__ __launch_bounds__(256)
void gemm_bias(const IT* __restrict__ X, const float* __restrict__ W,
               const float* __restrict__ bias, OT* __restrict__ Y,
               int n, int K, int O)
{
    __shared__ float As[16][68];   // [k][row], padded to kill bank conflicts
    __shared__ float Bs[16][68];
    const int tid = threadIdx.x;
    const int n0 = blockIdx.x * 64;
    const int o0 = blockIdx.y * 64;
    const int ty = tid / 16, tx = tid % 16;
    const int lk = tid % 16;       // k within tile
    const int lr = tid / 16;       // row base, 16 rows per pass

    float acc[4][4] = {};

    for (int k0 = 0; k0 < K; k0 += 16) {
        #pragma unroll
        for (int p = 0; p < 4; ++p) {
            int row = lr + p * 16;
            int gr = n0 + row;
            float v = 0.f;
            if (gr < n) {
                if constexpr (std::is_same<IT, u16>::value)
                    v = bflo((u32)X[(size_t)gr * K + k0 + lk]);
                else
                    v = X[(size_t)gr * K + k0 + lk];
            }
            As[lk][row] = v;
        }
        #pragma unroll
        for (int p = 0; p < 4; ++p) {
            int row = lr + p * 16;
            int go = o0 + row;     // O is a multiple of 64 -> always valid
            Bs[lk][row] = W[(size_t)go * K + k0 + lk];
        }
        __syncthreads();
        #pragma unroll
        for (int kk = 0; kk < 16; ++kk) {
            float4 a = *(const float4*)(&As[kk][ty * 4]);
            float4 b = *(const float4*)(&Bs[kk][tx * 4]);
            float av[4] = {a.x, a.y, a.z, a.w};
            float bv[4] = {b.x, b.y, b.z, b.w};
            #pragma unroll
            for (int i = 0; i < 4; ++i)
                #pragma unroll
                for (int j = 0; j < 4; ++j)
                    acc[i][j] = fmaf(av[i], bv[j], acc[i][j]);
        }
        __syncthreads();
    }

    float bv[4];
    #pragma unroll
    for (int j = 0; j < 4; ++j) bv[j] = bias[o0 + tx * 4 + j];

    #pragma unroll
    for (int i = 0; i < 4; ++i) {
        int gr = n0 + ty * 4 + i;
        if (gr >= n) continue;
        size_t base = (size_t)gr * O + o0 + tx * 4;
        if constexpr (std::is_same<OT, u16>::value) {
            ushort4 o;
            o.x = f2bf(acc[i][0] + bv[0]);
            o.y = f2bf(acc[i][1] + bv[1]);
            o.z = f2bf(acc[i][2] + bv[2]);
            o.w = f2bf(acc[i][3] + bv[3]);
            *(ushort4*)&Y[base] = o;
        } else {
            float4 o;
            o.x = acc[i][0] + bv[0];
            o.y = acc[i][1] + bv[1];
            o.z = acc[i][2] + bv[2];
            o.w = acc[i][3] + bv[3];
            *(float4*)&Y[base] = o;
        }
    }
}

// ---------------------------------------------------------------------------
__global__ __launch_bounds__(256)
void init_md(u32* __restrict__ mOrd, float* __restrict__ denom)
{
    int i = blockIdx.x * 256 + threadIdx.x;
    if (i < NN * NH) { mOrd[i] = 0u; denom[i] = 0.f; }
}

// one 64-lane wave per edge: lane covers 8 contiguous bf16 elements,
// 16-lane groups own one head each. alpha[e,h] = q[dst,h,:].k[src,h,:]/sqrt(C)
__global__ __launch_bounds__(256)
void edge_logits(const u16* __restrict__ Qb, const u16* __restrict__ Kb,
                 const int* __restrict__ src, const int* __restrict__ dst,
                 float* __restrict__ alpha, u32* __restrict__ mOrd)
{
    int e = blockIdx.x * 4 + (threadIdx.x >> 6);
    if (e >= NE) return;
    int lane = threadIdx.x & 63;
    int s = src[e], d = dst[e];
    uint4 qv = *((const uint4*)(Qb + (size_t)d * HC) + lane);
    uint4 kv = *((const uint4*)(Kb + (size_t)s * HC) + lane);
    float sum = bflo(qv.x) * bflo(kv.x) + bfhi(qv.x) * bfhi(kv.x)
              + bflo(qv.y) * bflo(kv.y) + bfhi(qv.y) * bfhi(kv.y)
              + bflo(qv.z) * bflo(kv.z) + bfhi(qv.z) * bfhi(kv.z)
              + bflo(qv.w) * bflo(kv.w) + bfhi(qv.w) * bfhi(kv.w);
    #pragma unroll
    for (int off = 1; off < 16; off <<= 1) sum += __shfl_xor(sum, off, 64);
    if ((lane & 15) == 0) {
        int h = lane >> 4;
        float a = sum * 0.08838834764831845f;
        alpha[e * NH + h] = a;
        atomicMax(&mOrd[d * NH + h], ordU(a));
    }
}

__global__ __launch_bounds__(256)
void edge_exp(const int* __restrict__ dst, float* __restrict__ alpha,
              const u32* __restrict__ mOrd, float* __restrict__ denom)
{
    int i = blockIdx.x * 256 + threadIdx.x;   // i = e*NH + h
    if (i >= NE * NH) return;
    int e = i >> 2, h = i & 3;
    int d = dst[e];
    float m = unordU(mOrd[d * NH + h]);
    float ex = __expf(alpha[i] - m);
    alpha[i] = ex;
    atomicAdd(&denom[d * NH + h], ex);
}

__global__ __launch_bounds__(256)
void edge_scatter(const u16* __restrict__ Vb, const int* __restrict__ src,
                  const int* __restrict__ dst, const float* __restrict__ alpha,
                  const float* __restrict__ denom, float* __restrict__ agg)
{
    int e = blockIdx.x * 4 + (threadIdx.x >> 6);
    if (e >= NE) return;
    int lane = threadIdx.x & 63;
    int s = src[e], d = dst[e];
    int h = lane >> 4;
    float a = alpha[e * NH + h] / (denom[d * NH + h] + 1e-16f);
    uint4 vv = *((const uint4*)(Vb + (size_t)s * HC) + lane);
    float* out = agg + (size_t)d * HC + lane * 8;
    atomicAdd(out + 0, bflo(vv.x) * a);
    atomicAdd(out + 1, bfhi(vv.x) * a);
    atomicAdd(out + 2, bflo(vv.y) * a);
    atomicAdd(out + 3, bfhi(vv.y) * a);
    atomicAdd(out + 4, bflo(vv.z) * a);
    atomicAdd(out + 5, bfhi(vv.z) * a);
    atomicAdd(out + 6, bflo(vv.w) * a);
    atomicAdd(out + 7, bfhi(vv.w) * a);
}

// Hb = bf16(relu(AGG))
__global__ __launch_bounds__(256)
void relu_bf16(const float* __restrict__ agg, u16* __restrict__ hb, size_t n4)
{
    size_t i = blockIdx.x * (size_t)blockDim.x + threadIdx.x;
    size_t stride = gridDim.x * (size_t)blockDim.x;
    for (; i < n4; i += stride) {
        float4 v = ((const float4*)agg)[i];
        ushort4 o;
        o.x = f2bf(fmaxf(v.x, 0.f));
        o.y = f2bf(fmaxf(v.y, 0.f));
        o.z = f2bf(fmaxf(v.z, 0.f));
        o.w = f2bf(fmaxf(v.w, 0.f));
        ((ushort4*)hb)[i] = o;
    }
}

__global__ __launch_bounds__(256)
void relu_ip(float* __restrict__ x, size_t n4)
{
    size_t i = blockIdx.x * (size_t)blockDim.x + threadIdx.x;
    size_t stride = gridDim.x * (size_t)blockDim.x;
    float4* x4 = (float4*)x;
    for (; i < n4; i += stride) {
        float4 v = x4[i];
        v.x = fmaxf(v.x, 0.f); v.y = fmaxf(v.y, 0.f);
        v.z = fmaxf(v.z, 0.f); v.w = fmaxf(v.w, 0.f);
        x4[i] = v;
    }
}

// ---------------------------------------------------------------------------
extern "C" void kernel_launch(void* const* d_in, const int* in_sizes, int n_in,
                              void* d_out, int out_size, void* d_ws, size_t ws_size,
                              hipStream_t stream)
{
    const float* x   = (const float*)d_in[0];
    const int* ei    = (const int*)d_in[1];
    const int* esrc  = ei;
    const int* edst  = ei + NE;
    const float* q0w = (const float*)d_in[2];  const float* q0b = (const float*)d_in[3];
    const float* k0w = (const float*)d_in[4];  const float* k0b = (const float*)d_in[5];
    const float* v0w = (const float*)d_in[6];  const float* v0b = (const float*)d_in[7];
    const float* s0w = (const float*)d_in[8];  const float* s0b = (const float*)d_in[9];
    const float* q1w = (const float*)d_in[10]; const float* q1b = (const float*)d_in[11];
    const float* k1w = (const float*)d_in[12]; const float* k1b = (const float*)d_in[13];
    const float* v1w = (const float*)d_in[14]; const float* v1b = (const float*)d_in[15];
    const float* s1w = (const float*)d_in[16]; const float* s1b = (const float*)d_in[17];
    const float* ow  = (const float*)d_in[18]; const float* obs = (const float*)d_in[19];

    // ---- workspace layout (~256 MB decimal = 244 MiB) ----
    char* p = (char*)d_ws;
    auto take = [&](size_t bytes) { void* r = (void*)p; p += (bytes + 255) & ~(size_t)255; return r; };
    u16*   Qb  = (u16*)take((size_t)NN * HC * 2);    // 51.2 MB
    u16*   Vb  = (u16*)take((size_t)NN * HC * 2);    // 51.2 MB
    u16*   Hb  = (u16*)take((size_t)NN * HC * 2);    // 51.2 MB (bf16 relu'd activations)
    float* AGG = (float*)take((size_t)NN * HC * 4);  // 102.4 MB (skip + scatter accum)

    // ---- scratch carved from d_out (76.8 MB, dead before final GEMM) ----
    char* dob = (char*)d_out;
    u16*   Kb    = (u16*)dob;                        // 51.2 MB
    float* alpha = (float*)(dob + 51200000);         // 6.4 MB
    u32*   mOrd  = (u32*)(dob + 57600000);           // 0.8 MB
    float* denom = (float*)(dob + 58400000);         // 0.8 MB  (total 59.2 < 76.8)

    dim3 blk(256);
    dim3 g512((NN + 63) / 64, HC / 64);
    dim3 g384((NN + 63) / 64, DD / 64);
    int ginit = (NN * NH + 255) / 256;
    int gedge = (NE + 3) / 4;
    int gexp  = (NE * NH + 255) / 256;
    size_t n4 = (size_t)NN * HC / 4;

    // ---------------- layer 0 (in dim 384, fp32 input) ----------------
    gemm_bias<float, u16>  <<<g512, blk, 0, stream>>>(x, q0w, q0b, Qb, NN, DD, HC);
    gemm_bias<float, u16>  <<<g512, blk, 0, stream>>>(x, k0w, k0b, Kb, NN, DD, HC);
    gemm_bias<float, u16>  <<<g512, blk, 0, stream>>>(x, v0w, v0b, Vb, NN, DD, HC);
    gemm_bias<float, float><<<g512, blk, 0, stream>>>(x, s0w, s0b, AGG, NN, DD, HC);
    init_md      <<<ginit, blk, 0, stream>>>(mOrd, denom);
    edge_logits  <<<gedge, blk, 0, stream>>>(Qb, Kb, esrc, edst, alpha, mOrd);
    edge_exp     <<<gexp,  blk, 0, stream>>>(edst, alpha, mOrd, denom);
    edge_scatter <<<gedge, blk, 0, stream>>>(Vb, esrc, edst, alpha, denom, AGG);
    relu_bf16    <<<2048,  blk, 0, stream>>>(AGG, Hb, n4);   // Hb = bf16(relu(AGG))

    // ---------------- layer 1 (in dim 512, bf16 input) ----------------
    gemm_bias<u16, u16>  <<<g512, blk, 0, stream>>>(Hb, q1w, q1b, Qb, NN, HC, HC);
    gemm_bias<u16, u16>  <<<g512, blk, 0, stream>>>(Hb, k1w, k1b, Kb, NN, HC, HC);
    gemm_bias<u16, u16>  <<<g512, blk, 0, stream>>>(Hb, v1w, v1b, Vb, NN, HC, HC);
    gemm_bias<u16, float><<<g512, blk, 0, stream>>>(Hb, s1w, s1b, AGG, NN, HC, HC);
    init_md      <<<ginit, blk, 0, stream>>>(mOrd, denom);
    edge_logits  <<<gedge, blk, 0, stream>>>(Qb, Kb, esrc, edst, alpha, mOrd);
    edge_exp     <<<gexp,  blk, 0, stream>>>(edst, alpha, mOrd, denom);
    edge_scatter <<<gedge, blk, 0, stream>>>(Vb, esrc, edst, alpha, denom, AGG);
    relu_ip      <<<2048,  blk, 0, stream>>>(AGG, n4);

    // ---------------- output projection (overwrites ALL of d_out) ----------------
    gemm_bias<float, float><<<g384, blk, 0, stream>>>(AGG, ow, obs, (float*)d_out, NN, HC, DD);
}

// Round 3
// 3186.380 us; speedup vs baseline: 4.4119x; 4.4119x over previous
//
#include <hip/hip_runtime.h>
#include <hip/hip_bf16.h>
#include <type_traits>

#define NN 50000   // nodes
#define NE 400000  // edges
#define DD 384     // input dim
#define NH 4       // heads
#define HC 512     // heads * per-head dim
// per-head dim C = 128, 1/sqrt(C) = 0.08838834764831845

typedef unsigned int u32;
typedef unsigned short u16;

__device__ __forceinline__ float bflo(u32 u){ return __uint_as_float(u << 16); }
__device__ __forceinline__ float bfhi(u32 u){ return __uint_as_float(u & 0xFFFF0000u); }
__device__ __forceinline__ u16 f2bf(float f){
    u32 u = __float_as_uint(f);
    u32 r = (u + 0x7FFFu + ((u >> 16) & 1u)) >> 16;   // round-to-nearest-even
    return (u16)r;
}

// ---------------------------------------------------------------------------
// Y[n,o] = sum_k X[n,k] * W[o,k] + b[o]
// X: n x K row-major (IT = float or u16/bf16), W: O x K row-major fp32.
// BM=BN=64, BK=16, 256 threads, 4x4 micro-tile. OT = u16 (bf16) or float.
// ---------------------------------------------------------------------------
template<typename IT, typename OT>
__global__ __launch_bounds__(256)
void gemm_bias(const IT* __restrict__ X, const float* __restrict__ W,
               const float* __restrict__ bias, OT* __restrict__ Y,
               int n, int K, int O)
{
    __shared__ float As[16][68];   // [k][row], padded to kill bank conflicts
    __shared__ float Bs[16][68];
    const int tid = threadIdx.x;
    const int n0 = blockIdx.x * 64;
    const int o0 = blockIdx.y * 64;
    const int ty = tid / 16, tx = tid % 16;
    const int lk = tid % 16;       // k within tile
    const int lr = tid / 16;       // row base, 16 rows per pass

    float acc[4][4] = {};

    for (int k0 = 0; k0 < K; k0 += 16) {
        #pragma unroll
        for (int p = 0; p < 4; ++p) {
            int row = lr + p * 16;
            int gr = n0 + row;
            float v = 0.f;
            if (gr < n) {
                if constexpr (std::is_same<IT, u16>::value)
                    v = bflo((u32)X[(size_t)gr * K + k0 + lk]);
                else
                    v = X[(size_t)gr * K + k0 + lk];
            }
            As[lk][row] = v;
        }
        #pragma unroll
        for (int p = 0; p < 4; ++p) {
            int row = lr + p * 16;
            int go = o0 + row;     // O is a multiple of 64 -> always valid
            Bs[lk][row] = W[(size_t)go * K + k0 + lk];
        }
        __syncthreads();
        #pragma unroll
        for (int kk = 0; kk < 16; ++kk) {
            float4 a = *(const float4*)(&As[kk][ty * 4]);
            float4 b = *(const float4*)(&Bs[kk][tx * 4]);
            float av[4] = {a.x, a.y, a.z, a.w};
            float bv[4] = {b.x, b.y, b.z, b.w};
            #pragma unroll
            for (int i = 0; i < 4; ++i)
                #pragma unroll
                for (int j = 0; j < 4; ++j)
                    acc[i][j] = fmaf(av[i], bv[j], acc[i][j]);
        }
        __syncthreads();
    }

    float bv[4];
    #pragma unroll
    for (int j = 0; j < 4; ++j) bv[j] = bias[o0 + tx * 4 + j];

    #pragma unroll
    for (int i = 0; i < 4; ++i) {
        int gr = n0 + ty * 4 + i;
        if (gr >= n) continue;
        size_t base = (size_t)gr * O + o0 + tx * 4;
        if constexpr (std::is_same<OT, u16>::value) {
            ushort4 o;
            o.x = f2bf(acc[i][0] + bv[0]);
            o.y = f2bf(acc[i][1] + bv[1]);
            o.z = f2bf(acc[i][2] + bv[2]);
            o.w = f2bf(acc[i][3] + bv[3]);
            *(ushort4*)&Y[base] = o;
        } else {
            float4 o;
            o.x = acc[i][0] + bv[0];
            o.y = acc[i][1] + bv[1];
            o.z = acc[i][2] + bv[2];
            o.w = acc[i][3] + bv[3];
            *(float4*)&Y[base] = o;
        }
    }
}

// ---------------------------------------------------------------------------
// CSR build: bucket edges by dst. Order within a bucket is atomic-race
// non-deterministic, which only permutes fp add order (within threshold).
// ---------------------------------------------------------------------------
__global__ __launch_bounds__(256)
void zero_deg(int* __restrict__ deg)
{
    int i = blockIdx.x * 256 + threadIdx.x;
    if (i < NN) deg[i] = 0;
}

__global__ __launch_bounds__(256)
void hist_dst(const int* __restrict__ dst, int* __restrict__ deg)
{
    int e = blockIdx.x * 256 + threadIdx.x;
    if (e < NE) atomicAdd(&deg[dst[e]], 1);
}

// single-block exclusive scan of deg[0..NN) -> rowptr, cursor
__global__ __launch_bounds__(1024)
void scan_deg(const int* __restrict__ deg, int* __restrict__ rowptr,
              int* __restrict__ cursor)
{
    __shared__ int buf[1024];
    __shared__ int carry;
    int tid = threadIdx.x;
    if (tid == 0) carry = 0;
    __syncthreads();
    for (int base = 0; base < NN; base += 1024) {
        int i = base + tid;
        int v = (i < NN) ? deg[i] : 0;
        buf[tid] = v;
        __syncthreads();
        #pragma unroll
        for (int off = 1; off < 1024; off <<= 1) {
            int t = (tid >= off) ? buf[tid - off] : 0;
            __syncthreads();
            buf[tid] += t;
            __syncthreads();
        }
        int excl = carry + buf[tid] - v;
        if (i < NN) { rowptr[i] = excl; cursor[i] = excl; }
        __syncthreads();
        if (tid == 0) carry += buf[1023];
        __syncthreads();
    }
    if (tid == 0) rowptr[NN] = NE;
}

__global__ __launch_bounds__(256)
void scatter_edges(const int* __restrict__ src, const int* __restrict__ dst,
                   int* __restrict__ cursor, int* __restrict__ esrc_ord)
{
    int e = blockIdx.x * 256 + threadIdx.x;
    if (e >= NE) return;
    int pos = atomicAdd(&cursor[dst[e]], 1);
    esrc_ord[pos] = src[e];
}

// ---------------------------------------------------------------------------
// Fused per-node attention: one 64-lane wave per dst node. Online softmax
// over in-edges; lane owns 8 contiguous channels, 16-lane group = one head.
// out = relu(agg + skip). OUT_BF16 -> write u16 outb, else float outf.
// ---------------------------------------------------------------------------
template<bool OUT_BF16>
__global__ __launch_bounds__(256)
void node_attn(const u16* __restrict__ Qb, const u16* __restrict__ Kb,
               const u16* __restrict__ Vb, const int* __restrict__ rowptr,
               const int* __restrict__ esrc, const float* __restrict__ skip,
               u16* __restrict__ outb, float* __restrict__ outf)
{
    int d = blockIdx.x * 4 + (threadIdx.x >> 6);
    if (d >= NN) return;
    int lane = threadIdx.x & 63;

    uint4 qv = *((const uint4*)(Qb + (size_t)d * HC) + lane);
    float q[8] = { bflo(qv.x), bfhi(qv.x), bflo(qv.y), bfhi(qv.y),
                   bflo(qv.z), bfhi(qv.z), bflo(qv.w), bfhi(qv.w) };

    int beg = rowptr[d], end = rowptr[d + 1];
    float m = -INFINITY, den = 0.f;
    float acc[8] = {};

    for (int i = beg; i < end; ++i) {
        int s = esrc[i];
        uint4 kv = *((const uint4*)(Kb + (size_t)s * HC) + lane);
        float sum = q[0] * bflo(kv.x) + q[1] * bfhi(kv.x)
                  + q[2] * bflo(kv.y) + q[3] * bfhi(kv.y)
                  + q[4] * bflo(kv.z) + q[5] * bfhi(kv.z)
                  + q[6] * bflo(kv.w) + q[7] * bfhi(kv.w);
        #pragma unroll
        for (int off = 1; off < 16; off <<= 1) sum += __shfl_xor(sum, off, 64);
        float alpha = sum * 0.08838834764831845f;

        float mnew  = fmaxf(m, alpha);
        float scale = __expf(m - mnew);      // first edge: exp(-inf)=0
        float p     = __expf(alpha - mnew);
        den = den * scale + p;

        uint4 vv = *((const uint4*)(Vb + (size_t)s * HC) + lane);
        acc[0] = acc[0] * scale + p * bflo(vv.x);
        acc[1] = acc[1] * scale + p * bfhi(vv.x);
        acc[2] = acc[2] * scale + p * bflo(vv.y);
        acc[3] = acc[3] * scale + p * bfhi(vv.y);
        acc[4] = acc[4] * scale + p * bflo(vv.z);
        acc[5] = acc[5] * scale + p * bfhi(vv.z);
        acc[6] = acc[6] * scale + p * bflo(vv.w);
        acc[7] = acc[7] * scale + p * bfhi(vv.w);
        m = mnew;
    }

    float inv = 1.f / (den + 1e-16f);
    size_t base = (size_t)d * HC + lane * 8;
    float4 s0 = *(const float4*)(skip + base);
    float4 s1 = *(const float4*)(skip + base + 4);
    float r[8];
    r[0] = fmaxf(acc[0] * inv + s0.x, 0.f);
    r[1] = fmaxf(acc[1] * inv + s0.y, 0.f);
    r[2] = fmaxf(acc[2] * inv + s0.z, 0.f);
    r[3] = fmaxf(acc[3] * inv + s0.w, 0.f);
    r[4] = fmaxf(acc[4] * inv + s1.x, 0.f);
    r[5] = fmaxf(acc[5] * inv + s1.y, 0.f);
    r[6] = fmaxf(acc[6] * inv + s1.z, 0.f);
    r[7] = fmaxf(acc[7] * inv + s1.w, 0.f);

    if constexpr (OUT_BF16) {
        uint4 o;
        o.x = (u32)f2bf(r[0]) | ((u32)f2bf(r[1]) << 16);
        o.y = (u32)f2bf(r[2]) | ((u32)f2bf(r[3]) << 16);
        o.z = (u32)f2bf(r[4]) | ((u32)f2bf(r[5]) << 16);
        o.w = (u32)f2bf(r[6]) | ((u32)f2bf(r[7]) << 16);
        *(uint4*)(outb + base) = o;
    } else {
        *(float4*)(outf + base)     = make_float4(r[0], r[1], r[2], r[3]);
        *(float4*)(outf + base + 4) = make_float4(r[4], r[5], r[6], r[7]);
    }
}

// ---------------------------------------------------------------------------
extern "C" void kernel_launch(void* const* d_in, const int* in_sizes, int n_in,
                              void* d_out, int out_size, void* d_ws, size_t ws_size,
                              hipStream_t stream)
{
    const float* x   = (const float*)d_in[0];
    const int* ei    = (const int*)d_in[1];
    const int* esrc  = ei;
    const int* edst  = ei + NE;
    const float* q0w = (const float*)d_in[2];  const float* q0b = (const float*)d_in[3];
    const float* k0w = (const float*)d_in[4];  const float* k0b = (const float*)d_in[5];
    const float* v0w = (const float*)d_in[6];  const float* v0b = (const float*)d_in[7];
    const float* s0w = (const float*)d_in[8];  const float* s0b = (const float*)d_in[9];
    const float* q1w = (const float*)d_in[10]; const float* q1b = (const float*)d_in[11];
    const float* k1w = (const float*)d_in[12]; const float* k1b = (const float*)d_in[13];
    const float* v1w = (const float*)d_in[14]; const float* v1b = (const float*)d_in[15];
    const float* s1w = (const float*)d_in[16]; const float* s1b = (const float*)d_in[17];
    const float* ow  = (const float*)d_in[18]; const float* obs = (const float*)d_in[19];

    // ---- workspace layout (~256 MB) ----
    char* p = (char*)d_ws;
    auto take = [&](size_t bytes) { void* r = (void*)p; p += (bytes + 255) & ~(size_t)255; return r; };
    u16*   Qb  = (u16*)take((size_t)NN * HC * 2);    // 51.2 MB
    u16*   Vb  = (u16*)take((size_t)NN * HC * 2);    // 51.2 MB
    u16*   Hb  = (u16*)take((size_t)NN * HC * 2);    // 51.2 MB (bf16 relu'd activations)
    float* AGG = (float*)take((size_t)NN * HC * 4);  // 102.4 MB (skip + agg accum)

    // ---- scratch carved from d_out (76.8 MB, dead before final GEMM) ----
    char* dob = (char*)d_out;
    u16* Kb       = (u16*)dob;                       // 51.2 MB
    int* deg      = (int*)(dob + 51200000);          // 0.2 MB
    int* rowptr   = (int*)(dob + 51400192);          // 0.2 MB (NN+1)
    int* cursor   = (int*)(dob + 51600384);          // 0.2 MB
    int* esrc_ord = (int*)(dob + 51800576);          // 1.6 MB   (total 53.4 < 76.8)

    dim3 blk(256);
    dim3 g512((NN + 63) / 64, HC / 64);
    dim3 g384((NN + 63) / 64, DD / 64);
    int gN   = (NN + 255) / 256;
    int gE   = (NE + 255) / 256;
    int gnod = (NN + 3) / 4;

    // ---------------- CSR build (shared by both layers) ----------------
    zero_deg      <<<gN, blk, 0, stream>>>(deg);
    hist_dst      <<<gE, blk, 0, stream>>>(edst, deg);
    scan_deg      <<<1, 1024, 0, stream>>>(deg, rowptr, cursor);
    scatter_edges <<<gE, blk, 0, stream>>>(esrc, edst, cursor, esrc_ord);

    // ---------------- layer 0 (in dim 384, fp32 input) ----------------
    gemm_bias<float, u16>  <<<g512, blk, 0, stream>>>(x, q0w, q0b, Qb, NN, DD, HC);
    gemm_bias<float, u16>  <<<g512, blk, 0, stream>>>(x, k0w, k0b, Kb, NN, DD, HC);
    gemm_bias<float, u16>  <<<g512, blk, 0, stream>>>(x, v0w, v0b, Vb, NN, DD, HC);
    gemm_bias<float, float><<<g512, blk, 0, stream>>>(x, s0w, s0b, AGG, NN, DD, HC);
    node_attn<true><<<gnod, blk, 0, stream>>>(Qb, Kb, Vb, rowptr, esrc_ord, AGG, Hb, nullptr);

    // ---------------- layer 1 (in dim 512, bf16 input) ----------------
    gemm_bias<u16, u16>  <<<g512, blk, 0, stream>>>(Hb, q1w, q1b, Qb, NN, HC, HC);
    gemm_bias<u16, u16>  <<<g512, blk, 0, stream>>>(Hb, k1w, k1b, Kb, NN, HC, HC);
    gemm_bias<u16, u16>  <<<g512, blk, 0, stream>>>(Hb, v1w, v1b, Vb, NN, HC, HC);
    gemm_bias<u16, float><<<g512, blk, 0, stream>>>(Hb, s1w, s1b, AGG, NN, HC, HC);
    node_attn<false><<<gnod, blk, 0, stream>>>(Qb, Kb, Vb, rowptr, esrc_ord, AGG, nullptr, AGG);

    // ---------------- output projection (overwrites ALL of d_out) ----------------
    gemm_bias<float, float><<<g384, blk, 0, stream>>>(AGG, ow, obs, (float*)d_out, NN, HC, DD);
}

// Round 4
// 1015.954 us; speedup vs baseline: 13.8373x; 3.1363x over previous
//
#include <hip/hip_runtime.h>
#include <hip/hip_bf16.h>

#define NN 50000   // nodes
#define NE 400000  // edges
#define DD 384     // input dim
#define HC 512     // heads * per-head dim (4 heads x 128)

typedef unsigned int u32;
typedef unsigned short u16;
typedef __attribute__((ext_vector_type(8))) short bf16x8;  // 8 bf16 (4 VGPRs)
typedef __attribute__((ext_vector_type(4))) float f32x4;

#define AS1 __attribute__((address_space(1)))
#define AS3 __attribute__((address_space(3)))

__device__ __forceinline__ float bflo(u32 u){ return __uint_as_float(u << 16); }
__device__ __forceinline__ float bfhi(u32 u){ return __uint_as_float(u & 0xFFFF0000u); }
__device__ __forceinline__ u16 f2bf(float f){
    u32 u = __float_as_uint(f);
    return (u16)((u + 0x7FFFu + ((u >> 16) & 1u)) >> 16);   // RNE
}
__device__ __forceinline__ u32 pack2(float a, float b){
    return (u32)f2bf(a) | ((u32)f2bf(b) << 16);
}

// ---------------------------------------------------------------------------
// MFMA GEMM: Y[n, O] = A[n, K] * W[O, K]^T + bias
// A: fp32 (AFP32) or bf16. W: bf16 row-major. K % 64 == 0, O % 128 == 0.
// Tile 128x128, BK=64, 256 threads = 4 waves (2x2), wave owns 64x64.
// LDS tiles [128 rows][128 bytes], XOR-swizzled: chunk ^= (row & 7).
// QKVS: O=2048, each 128-col block writes one of {oQ,oK,oV,oS} (bf16, stride 512).
// else: fp32 out oF, stride Ototal.
// ---------------------------------------------------------------------------
template<bool AFP32, bool QKVS>
__global__ __launch_bounds__(256)
void gemm_mfma(const void* __restrict__ Ap, const u16* __restrict__ Wb,
               const float* __restrict__ bias,
               u16* __restrict__ oQ, u16* __restrict__ oK,
               u16* __restrict__ oV, u16* __restrict__ oS,
               float* __restrict__ oF,
               int n, int K, int Ototal)
{
    __shared__ char smA[128 * 128];
    __shared__ char smB[128 * 128];

    const int tid  = threadIdx.x;
    const int lane = tid & 63;
    const int w    = tid >> 6;
    const int wr   = w >> 1, wc = w & 1;
    const int m0   = blockIdx.x * 128;
    const int o0   = blockIdx.y * 128;
    const int r16  = lane & 15;
    const int kq   = lane >> 4;            // 0..3
    const int swz  = (r16 & 7) << 4;       // read-side XOR (tile row & 7) == (r16 & 7)

    f32x4 acc[4][4] = {};

    const int nkt = K >> 6;
    for (int kt = 0; kt < nkt; ++kt) {
        const int k0 = kt << 6;
        __syncthreads();                   // protect LDS from previous reads
        // ---- stage B (bf16) via global_load_lds, source pre-swizzled ----
        #pragma unroll
        for (int p = 0; p < 4; ++p) {
            int ci = p * 256 + tid;        // 16B chunk index, 8 chunks/row
            int row = ci >> 3, pc = ci & 7;
            int lc = pc ^ (row & 7);       // logical chunk feeding physical pc
            const u16* g = Wb + (size_t)(o0 + row) * K + k0 + lc * 8;
            __builtin_amdgcn_global_load_lds((const AS1 u32*)g,
                                             (AS3 u32*)(smB + ci * 16), 16, 0, 0);
        }
        // ---- stage A ----
        if constexpr (AFP32) {             // fp32 -> bf16 convert via registers
            const float* Af = (const float*)Ap;
            #pragma unroll
            for (int p = 0; p < 4; ++p) {
                int ci = p * 256 + tid;
                int row = ci >> 3, lc = ci & 7;
                int gr = m0 + row; if (gr >= n) gr = n - 1;
                const float* g = Af + (size_t)gr * K + k0 + lc * 8;
                float4 f0 = *(const float4*)g;
                float4 f1 = *(const float4*)(g + 4);
                uint4 o;
                o.x = pack2(f0.x, f0.y); o.y = pack2(f0.z, f0.w);
                o.z = pack2(f1.x, f1.y); o.w = pack2(f1.z, f1.w);
                int pc = lc ^ (row & 7);
                *(uint4*)(smA + row * 128 + pc * 16) = o;
            }
        } else {
            const u16* Ab = (const u16*)Ap;
            #pragma unroll
            for (int p = 0; p < 4; ++p) {
                int ci = p * 256 + tid;
                int row = ci >> 3, pc = ci & 7;
                int lc = pc ^ (row & 7);
                int gr = m0 + row; if (gr >= n) gr = n - 1;
                const u16* g = Ab + (size_t)gr * K + k0 + lc * 8;
                __builtin_amdgcn_global_load_lds((const AS1 u32*)g,
                                                 (AS3 u32*)(smA + ci * 16), 16, 0, 0);
            }
        }
        __syncthreads();                   // compiler drains vmcnt/lgkm before barrier
        // ---- compute: 32 MFMA / wave / K-step ----
        const char* pa = smA + (wr * 64) * 128;
        const char* pb = smB + (wc * 64) * 128;
        #pragma unroll
        for (int kk = 0; kk < 2; ++kk) {
            const int kb = kk * 64 + kq * 16;    // byte offset of lane's 8 bf16
            bf16x8 av[4], bv[4];
            #pragma unroll
            for (int i = 0; i < 4; ++i) {
                av[i] = *(const bf16x8*)(pa + (i * 16 + r16) * 128 + (kb ^ swz));
                bv[i] = *(const bf16x8*)(pb + (i * 16 + r16) * 128 + (kb ^ swz));
            }
            #pragma unroll
            for (int mi = 0; mi < 4; ++mi)
                #pragma unroll
                for (int ni = 0; ni < 4; ++ni)
                    acc[mi][ni] = __builtin_amdgcn_mfma_f32_16x16x32_bf16(
                        av[mi], bv[ni], acc[mi][ni], 0, 0, 0);
        }
    }

    // ---- epilogue: C/D layout col = lane&15, row = (lane>>4)*4 + reg ----
    if constexpr (QKVS) {
        const int q = o0 >> 9;             // BN=128 divides 512 -> block-uniform target
        u16* outp = (q == 0) ? oQ : (q == 1) ? oK : (q == 2) ? oV : oS;
        const int cb = (o0 & 511) + wc * 64;
        #pragma unroll
        for (int ni = 0; ni < 4; ++ni) {
            int col = cb + ni * 16 + r16;
            float b = bias[o0 + wc * 64 + ni * 16 + r16];
            #pragma unroll
            for (int mi = 0; mi < 4; ++mi)
                #pragma unroll
                for (int r = 0; r < 4; ++r) {
                    int gr = m0 + wr * 64 + mi * 16 + kq * 4 + r;
                    if (gr < n) outp[(size_t)gr * 512 + col] = f2bf(acc[mi][ni][r] + b);
                }
        }
    } else {
        const int cb = o0 + wc * 64;
        #pragma unroll
        for (int ni = 0; ni < 4; ++ni) {
            int col = cb + ni * 16 + r16;
            float b = bias[col];
            #pragma unroll
            for (int mi = 0; mi < 4; ++mi)
                #pragma unroll
                for (int r = 0; r < 4; ++r) {
                    int gr = m0 + wr * 64 + mi * 16 + kq * 4 + r;
                    if (gr < n) oF[(size_t)gr * Ototal + col] = acc[mi][ni][r] + b;
                }
        }
    }
}

// ---------------------------------------------------------------------------
// weight fp32 -> bf16 convert (count % 8 == 0)
__global__ __launch_bounds__(256)
void cvt_w(const float* __restrict__ src, u16* __restrict__ dst, int n8)
{
    int i = blockIdx.x * 256 + threadIdx.x;
    if (i >= n8) return;
    const float4* s = (const float4*)src + (size_t)i * 2;
    float4 f0 = s[0], f1 = s[1];
    uint4 o;
    o.x = pack2(f0.x, f0.y); o.y = pack2(f0.z, f0.w);
    o.z = pack2(f1.x, f1.y); o.w = pack2(f1.z, f1.w);
    ((uint4*)dst)[i] = o;
}

// bias arena: [0..2047]=layer0 qkvs, [2048..4095]=layer1 qkvs, [4096..4479]=out
__global__ __launch_bounds__(256)
void pack_bias(const float* q0, const float* k0, const float* v0, const float* s0,
               const float* q1, const float* k1, const float* v1, const float* s1,
               const float* ob, float* __restrict__ dst)
{
    int i = blockIdx.x * 256 + threadIdx.x;
    if (i >= 4480) return;
    float v;
    if (i < 2048) {
        int j = i & 511, q = i >> 9;
        v = (q == 0 ? q0 : q == 1 ? k0 : q == 2 ? v0 : s0)[j];
    } else if (i < 4096) {
        int j = i - 2048; int q = j >> 9; j &= 511;
        v = (q == 0 ? q1 : q == 1 ? k1 : q == 2 ? v1 : s1)[j];
    } else {
        v = ob[i - 4096];
    }
    dst[i] = v;
}

// ---------------------------------------------------------------------------
// CSR build (order within bucket nondeterministic -> only permutes fp adds)
// ---------------------------------------------------------------------------
__global__ __launch_bounds__(256)
void zero_deg(int* __restrict__ deg)
{
    int i = blockIdx.x * 256 + threadIdx.x;
    if (i < NN) deg[i] = 0;
}

__global__ __launch_bounds__(256)
void hist_dst(const int* __restrict__ dst, int* __restrict__ deg)
{
    int e = blockIdx.x * 256 + threadIdx.x;
    if (e < NE) atomicAdd(&deg[dst[e]], 1);
}

__global__ __launch_bounds__(1024)
void scan_deg(const int* __restrict__ deg, int* __restrict__ rowptr,
              int* __restrict__ cursor)
{
    __shared__ int buf[1024];
    __shared__ int carry;
    int tid = threadIdx.x;
    if (tid == 0) carry = 0;
    __syncthreads();
    for (int base = 0; base < NN; base += 1024) {
        int i = base + tid;
        int v = (i < NN) ? deg[i] : 0;
        buf[tid] = v;
        __syncthreads();
        #pragma unroll
        for (int off = 1; off < 1024; off <<= 1) {
            int t = (tid >= off) ? buf[tid - off] : 0;
            __syncthreads();
            buf[tid] += t;
            __syncthreads();
        }
        int excl = carry + buf[tid] - v;
        if (i < NN) { rowptr[i] = excl; cursor[i] = excl; }
        __syncthreads();
        if (tid == 0) carry += buf[1023];
        __syncthreads();
    }
    if (tid == 0) rowptr[NN] = NE;
}

__global__ __launch_bounds__(256)
void scatter_edges(const int* __restrict__ src, const int* __restrict__ dst,
                   int* __restrict__ cursor, int* __restrict__ esrc_ord)
{
    int e = blockIdx.x * 256 + threadIdx.x;
    if (e >= NE) return;
    int pos = atomicAdd(&cursor[dst[e]], 1);
    esrc_ord[pos] = src[e];
}

// ---------------------------------------------------------------------------
// Fused per-node attention: one 64-lane wave per dst node; online softmax.
// Lane owns 8 contiguous channels; 16-lane group = one head.
// out = bf16(relu(agg + skip)), skip is bf16.
// ---------------------------------------------------------------------------
__global__ __launch_bounds__(256)
void node_attn(const u16* __restrict__ Qb, const u16* __restrict__ Kb,
               const u16* __restrict__ Vb, const int* __restrict__ rowptr,
               const int* __restrict__ esrc, const u16* __restrict__ skipb,
               u16* __restrict__ outb)
{
    int d = blockIdx.x * 4 + (threadIdx.x >> 6);
    if (d >= NN) return;
    int lane = threadIdx.x & 63;

    uint4 qv = *((const uint4*)(Qb + (size_t)d * HC) + lane);
    float q[8] = { bflo(qv.x), bfhi(qv.x), bflo(qv.y), bfhi(qv.y),
                   bflo(qv.z), bfhi(qv.z), bflo(qv.w), bfhi(qv.w) };

    int beg = rowptr[d], end = rowptr[d + 1];
    float m = -INFINITY, den = 0.f;
    float acc[8] = {};

    for (int i = beg; i < end; ++i) {
        int s = esrc[i];
        uint4 kv = *((const uint4*)(Kb + (size_t)s * HC) + lane);
        float sum = q[0] * bflo(kv.x) + q[1] * bfhi(kv.x)
                  + q[2] * bflo(kv.y) + q[3] * bfhi(kv.y)
                  + q[4] * bflo(kv.z) + q[5] * bfhi(kv.z)
                  + q[6] * bflo(kv.w) + q[7] * bfhi(kv.w);
        #pragma unroll
        for (int off = 1; off < 16; off <<= 1) sum += __shfl_xor(sum, off, 64);
        float alpha = sum * 0.08838834764831845f;

        float mnew  = fmaxf(m, alpha);
        float scale = __expf(m - mnew);      // first edge: exp(-inf)=0
        float p     = __expf(alpha - mnew);
        den = den * scale + p;

        uint4 vv = *((const uint4*)(Vb + (size_t)s * HC) + lane);
        acc[0] = acc[0] * scale + p * bflo(vv.x);
        acc[1] = acc[1] * scale + p * bfhi(vv.x);
        acc[2] = acc[2] * scale + p * bflo(vv.y);
        acc[3] = acc[3] * scale + p * bfhi(vv.y);
        acc[4] = acc[4] * scale + p * bflo(vv.z);
        acc[5] = acc[5] * scale + p * bfhi(vv.z);
        acc[6] = acc[6] * scale + p * bflo(vv.w);
        acc[7] = acc[7] * scale + p * bfhi(vv.w);
        m = mnew;
    }

    float inv = 1.f / (den + 1e-16f);
    size_t base = (size_t)d * HC + lane * 8;
    uint4 sv = *((const uint4*)(skipb + base));
    float sk[8] = { bflo(sv.x), bfhi(sv.x), bflo(sv.y), bfhi(sv.y),
                    bflo(sv.z), bfhi(sv.z), bflo(sv.w), bfhi(sv.w) };
    uint4 o;
    o.x = pack2(fmaxf(acc[0] * inv + sk[0], 0.f), fmaxf(acc[1] * inv + sk[1], 0.f));
    o.y = pack2(fmaxf(acc[2] * inv + sk[2], 0.f), fmaxf(acc[3] * inv + sk[3], 0.f));
    o.z = pack2(fmaxf(acc[4] * inv + sk[4], 0.f), fmaxf(acc[5] * inv + sk[5], 0.f));
    o.w = pack2(fmaxf(acc[6] * inv + sk[6], 0.f), fmaxf(acc[7] * inv + sk[7], 0.f));
    *(uint4*)(outb + base) = o;
}

// ---------------------------------------------------------------------------
extern "C" void kernel_launch(void* const* d_in, const int* in_sizes, int n_in,
                              void* d_out, int out_size, void* d_ws, size_t ws_size,
                              hipStream_t stream)
{
    const float* x   = (const float*)d_in[0];
    const int* ei    = (const int*)d_in[1];
    const int* esrc  = ei;
    const int* edst  = ei + NE;
    const float* q0w = (const float*)d_in[2];  const float* q0b = (const float*)d_in[3];
    const float* k0w = (const float*)d_in[4];  const float* k0b = (const float*)d_in[5];
    const float* v0w = (const float*)d_in[6];  const float* v0b = (const float*)d_in[7];
    const float* s0w = (const float*)d_in[8];  const float* s0b = (const float*)d_in[9];
    const float* q1w = (const float*)d_in[10]; const float* q1b = (const float*)d_in[11];
    const float* k1w = (const float*)d_in[12]; const float* k1b = (const float*)d_in[13];
    const float* v1w = (const float*)d_in[14]; const float* v1b = (const float*)d_in[15];
    const float* s1w = (const float*)d_in[16]; const float* s1b = (const float*)d_in[17];
    const float* ow  = (const float*)d_in[18]; const float* obs = (const float*)d_in[19];

    // ---- workspace (~209 MB of the >=256 MB proven available) ----
    char* p = (char*)d_ws;
    auto take = [&](size_t bytes) { void* r = (void*)p; p += (bytes + 255) & ~(size_t)255; return r; };
    u16*   Qb     = (u16*)take((size_t)NN * HC * 2);       // 51.2 MB
    u16*   Vb     = (u16*)take((size_t)NN * HC * 2);       // 51.2 MB
    u16*   Hb     = (u16*)take((size_t)NN * HC * 2);       // 51.2 MB
    u16*   Sb     = (u16*)take((size_t)NN * HC * 2);       // 51.2 MB (bf16 skip)
    u16*   Wc0    = (u16*)take((size_t)2048 * DD * 2);     // 1.57 MB
    u16*   Wc1    = (u16*)take((size_t)2048 * HC * 2);     // 2.10 MB
    u16*   WcO    = (u16*)take((size_t)DD * HC * 2);       // 0.39 MB
    float* barena = (float*)take(4480 * 4);                // 17.9 KB

    // ---- scratch carved from d_out (dead before final GEMM overwrites all) ----
    char* dob = (char*)d_out;
    u16* Kb       = (u16*)dob;                             // 51.2 MB
    int* deg      = (int*)(dob + 51200000);
    int* rowptr   = (int*)(dob + 51400192);                // NN+1
    int* cursor   = (int*)(dob + 51600384);
    int* esrc_ord = (int*)(dob + 51800576);                // 1.6 MB

    dim3 blk(256);
    int gN   = (NN + 255) / 256;
    int gE   = (NE + 255) / 256;
    int gnod = (NN + 3) / 4;
    dim3 gq((NN + 127) / 128, 16);      // QKVS GEMM: O=2048
    dim3 go((NN + 127) / 128, 3);       // out-proj: O=384

    // ---- weight/bias prep ----
    pack_bias<<<(4480 + 255) / 256, blk, 0, stream>>>(q0b, k0b, v0b, s0b,
                                                      q1b, k1b, v1b, s1b, obs, barena);
    const int w0n8 = 512 * DD / 8, w1n8 = 512 * HC / 8, won8 = DD * HC / 8;
    cvt_w<<<(w0n8 + 255) / 256, blk, 0, stream>>>(q0w, Wc0 + 0 * 512 * DD, w0n8);
    cvt_w<<<(w0n8 + 255) / 256, blk, 0, stream>>>(k0w, Wc0 + 1 * 512 * DD, w0n8);
    cvt_w<<<(w0n8 + 255) / 256, blk, 0, stream>>>(v0w, Wc0 + 2 * 512 * DD, w0n8);
    cvt_w<<<(w0n8 + 255) / 256, blk, 0, stream>>>(s0w, Wc0 + 3 * 512 * DD, w0n8);
    cvt_w<<<(w1n8 + 255) / 256, blk, 0, stream>>>(q1w, Wc1 + 0 * 512 * HC, w1n8);
    cvt_w<<<(w1n8 + 255) / 256, blk, 0, stream>>>(k1w, Wc1 + 1 * 512 * HC, w1n8);
    cvt_w<<<(w1n8 + 255) / 256, blk, 0, stream>>>(v1w, Wc1 + 2 * 512 * HC, w1n8);
    cvt_w<<<(w1n8 + 255) / 256, blk, 0, stream>>>(s1w, Wc1 + 3 * 512 * HC, w1n8);
    cvt_w<<<(won8 + 255) / 256, blk, 0, stream>>>(ow, WcO, won8);

    // ---- CSR build ----
    zero_deg      <<<gN, blk, 0, stream>>>(deg);
    hist_dst      <<<gE, blk, 0, stream>>>(edst, deg);
    scan_deg      <<<1, 1024, 0, stream>>>(deg, rowptr, cursor);
    scatter_edges <<<gE, blk, 0, stream>>>(esrc, edst, cursor, esrc_ord);

    // ---- layer 0 (A = x fp32, K=384) ----
    gemm_mfma<true, true><<<gq, blk, 0, stream>>>(x, Wc0, barena,
                                                  Qb, Kb, Vb, Sb, nullptr, NN, DD, 2048);
    node_attn<<<gnod, blk, 0, stream>>>(Qb, Kb, Vb, rowptr, esrc_ord, Sb, Hb);

    // ---- layer 1 (A = Hb bf16, K=512) ----
    gemm_mfma<false, true><<<gq, blk, 0, stream>>>(Hb, Wc1, barena + 2048,
                                                   Qb, Kb, Vb, Sb, nullptr, NN, HC, 2048);
    node_attn<<<gnod, blk, 0, stream>>>(Qb, Kb, Vb, rowptr, esrc_ord, Sb, Hb);

    // ---- output projection (fp32 out, overwrites ALL of d_out) ----
    gemm_mfma<false, false><<<go, blk, 0, stream>>>(Hb, WcO, barena + 4096,
                                                    nullptr, nullptr, nullptr, nullptr,
                                                    (float*)d_out, NN, HC, DD);
}